// Round 4
// baseline (674.154 us; speedup 1.0000x reference)
//
#include <hip/hip_runtime.h>
#include <math.h>

#define NTOK 8192
#define DDIM 256
#define KCB  4096
#define BT   128     // tokens per block
#define BK   128     // codes per block
#define DC   64      // d-chunk
#define PS   132     // LDS row stride in floats (16B-aligned float4 reads)
#define GEPS 1e-10f

// ws layout (float units): esq[4096], zsq[8192], key u64[8192], hist[4096], comm[1]
#define WS_ESQ  0
#define WS_ZSQ  (WS_ESQ + KCB)        // 4096
#define WS_KEY  (WS_ZSQ + NTOK)       // 12288 (byte off 49152, 8B aligned)
#define WS_HIST (WS_KEY + 2 * NTOK)   // 28672
#define WS_COMM (WS_HIST + KCB)       // 32768  -> ~131 KB total

// out offsets (f32 elements): z_q, embedding, indices, commitment, perplexity, entropy
#define OUT_ZQ   0
#define OUT_EMB  (NTOK * DDIM)
#define OUT_IDX  (2 * NTOK * DDIM)
#define OUT_SCAL (2 * NTOK * DDIM + NTOK)

// ---------------- prep: e_sq, z_sq, zero key/hist/comm ----------------
__global__ __launch_bounds__(256) void k_prep(const float* __restrict__ cb,
                                              const float* __restrict__ z,
                                              float* __restrict__ esq,
                                              float* __restrict__ zsq,
                                              float* __restrict__ keyf,
                                              float* __restrict__ hist,
                                              float* __restrict__ comm) {
  const int lane = threadIdx.x & 63;
  const int wv   = threadIdx.x >> 6;
  const int row  = blockIdx.x * 4 + wv;   // 0..12287
  const float* src = (row < KCB) ? (cb + (size_t)row * DDIM)
                                 : (z  + (size_t)(row - KCB) * DDIM);
  float4 v = *(const float4*)(src + 4 * lane);
  float s = v.x * v.x + v.y * v.y + v.z * v.z + v.w * v.w;
  #pragma unroll
  for (int o = 32; o > 0; o >>= 1) s += __shfl_down(s, o);
  if (lane == 0) {
    if (row < KCB) esq[row] = s;
    else           zsq[row - KCB] = s;
  }
  const int gid = blockIdx.x * 256 + threadIdx.x;
  if (gid < 2 * NTOK) keyf[gid] = 0.0f;                       // zero u64 keys
  else if (gid < 2 * NTOK + KCB) hist[gid - 2 * NTOK] = 0.0f; // zero hist
  else if (gid == 2 * NTOK + KCB) comm[0] = 0.0f;
}

// ---------------- fused distance-GEMM + gumbel + argmax (atomicMax merge) ----------------
// grid (NTOK/BT, KCB/BK) = (64, 32), block 256. Tile 128 tok x 128 k, thread 8x8.
__global__ __launch_bounds__(256, 2) void k_score(const float* __restrict__ z,
                                                  const float* __restrict__ u,
                                                  const float* __restrict__ cb,
                                                  const float* __restrict__ esq,
                                                  const float* __restrict__ zsq,
                                                  unsigned long long* __restrict__ key) {
  __shared__ float zsm[DC][PS];   // [d][t] transposed z chunk
  __shared__ float csm[DC][PS];   // [d][k] transposed codebook chunk

  const int tid  = threadIdx.x;
  const int tok0 = blockIdx.x * BT;
  const int kb   = blockIdx.y * BK;
  const int tx = tid & 15;        // k sub-tile: 8*tx .. 8*tx+7
  const int ty = tid >> 4;        // token sub-tile: 8*ty .. 8*ty+7 (also staging row group)

  float acc[8][8] = {};
  float4 zr[8], cr[8];

  // prologue: prefetch d-chunk 0 into registers (staging map: row ty+16m, cols 4*tx)
  #pragma unroll
  for (int m = 0; m < 8; ++m) {
    zr[m] = *(const float4*)(z  + (size_t)(tok0 + ty + 16 * m) * DDIM + 4 * tx);
    cr[m] = *(const float4*)(cb + (size_t)(kb  + ty + 16 * m) * DDIM + 4 * tx);
  }

  for (int dc = 0; dc < DDIM / DC; ++dc) {
    // write staged registers to LDS (transposed)
    #pragma unroll
    for (int m = 0; m < 8; ++m) {
      const int t = ty + 16 * m, r = 4 * tx;
      zsm[r + 0][t] = zr[m].x; zsm[r + 1][t] = zr[m].y;
      zsm[r + 2][t] = zr[m].z; zsm[r + 3][t] = zr[m].w;
      csm[r + 0][t] = cr[m].x; csm[r + 1][t] = cr[m].y;
      csm[r + 2][t] = cr[m].z; csm[r + 3][t] = cr[m].w;
    }
    __syncthreads();

    // prefetch next chunk (overlaps with compute below)
    if (dc < DDIM / DC - 1) {
      const int d0 = (dc + 1) * DC;
      #pragma unroll
      for (int m = 0; m < 8; ++m) {
        zr[m] = *(const float4*)(z  + (size_t)(tok0 + ty + 16 * m) * DDIM + d0 + 4 * tx);
        cr[m] = *(const float4*)(cb + (size_t)(kb  + ty + 16 * m) * DDIM + d0 + 4 * tx);
      }
    }

    // compute: bit-identical accumulation order to round 3 (per-chunk ck, then acc += ck)
    float ck[8][8] = {};
    #pragma unroll
    for (int d = 0; d < DC; ++d) {
      const float4 za = *(const float4*)&zsm[d][8 * ty];
      const float4 zb = *(const float4*)&zsm[d][8 * ty + 4];
      const float4 ca = *(const float4*)&csm[d][8 * tx];
      const float4 cc = *(const float4*)&csm[d][8 * tx + 4];
      const float zf[8] = {za.x, za.y, za.z, za.w, zb.x, zb.y, zb.z, zb.w};
      const float cf[8] = {ca.x, ca.y, ca.z, ca.w, cc.x, cc.y, cc.z, cc.w};
      #pragma unroll
      for (int i = 0; i < 8; ++i)
        #pragma unroll
        for (int j = 0; j < 8; ++j) ck[i][j] += zf[i] * cf[j];
    }
    #pragma unroll
    for (int i = 0; i < 8; ++i)
      #pragma unroll
      for (int j = 0; j < 8; ++j) acc[i][j] += ck[i][j];
    __syncthreads();
  }

  // scores + per-thread argmax (k ascending within thread: strict > keeps lowest k)
  const float4 ea = *(const float4*)(esq + kb + 8 * tx);
  const float4 eb = *(const float4*)(esq + kb + 8 * tx + 4);
  const float esa[8] = {ea.x, ea.y, ea.z, ea.w, eb.x, eb.y, eb.z, eb.w};

  float bv[8];
  int   bj[8];
  #pragma unroll
  for (int i = 0; i < 8; ++i) {
    const int tok = tok0 + 8 * ty + i;
    const float zq = zsq[tok];
    const float4 ua = *(const float4*)(u + (size_t)tok * KCB + kb + 8 * tx);
    const float4 ub = *(const float4*)(u + (size_t)tok * KCB + kb + 8 * tx + 4);
    const float uu[8] = {ua.x, ua.y, ua.z, ua.w, ub.x, ub.y, ub.z, ub.w};
    bv[i] = -3.402823e38f; bj[i] = kb + 8 * tx;
    #pragma unroll
    for (int j = 0; j < 8; ++j) {
      const float g = -logf(-logf(uu[j] + GEPS) + GEPS);
      const float s = -((zq + esa[j]) - 2.0f * acc[i][j]) + g;
      if (s > bv[i]) { bv[i] = s; bj[i] = kb + 8 * tx + j; }
    }
  }

  // block merge across tx groups (overlay on zsm/csm), then global atomicMax
  __syncthreads();
  float* pv = &zsm[0][0];          // 128 x 16 floats
  int*   pi = (int*)&csm[0][0];    // 128 x 16 ints
  #pragma unroll
  for (int i = 0; i < 8; ++i) {
    pv[(8 * ty + i) * 16 + tx] = bv[i];
    pi[(8 * ty + i) * 16 + tx] = bj[i];
  }
  __syncthreads();
  if (tid < BT) {
    float best  = pv[tid * 16];
    int   besti = pi[tid * 16];
    for (int x = 1; x < 16; ++x) {   // ascending tx = ascending k
      const float v = pv[tid * 16 + x];
      if (v > best) { best = v; besti = pi[tid * 16 + x]; }
    }
    // order-preserving f32->u32 map; low word = 4095-k so ties pick lowest k
    unsigned int b = __float_as_uint(best);
    b = (b & 0x80000000u) ? ~b : (b | 0x80000000u);
    const unsigned long long kk =
        ((unsigned long long)b << 32) | (unsigned int)(KCB - 1 - besti);
    atomicMax(&key[tok0 + tid], kk);
  }
}

// ---------------- finalize per token: decode key, gather, outputs ----------------
__global__ __launch_bounds__(256) void k_final(const float* __restrict__ z,
                                               const float* __restrict__ cb,
                                               const unsigned long long* __restrict__ key,
                                               float* __restrict__ out,
                                               float* __restrict__ hist,
                                               float* __restrict__ comm) {
  const int lane = threadIdx.x & 63;
  const int wv   = threadIdx.x >> 6;
  const int tok  = blockIdx.x * 4 + wv;

  const unsigned long long kk = key[tok];
  int bi = KCB - 1 - (int)(kk & 0xFFFFFFFFu);
  bi = min(max(bi, 0), KCB - 1);

  const float4 c  = *(const float4*)(cb + (size_t)bi * DDIM + 4 * lane);
  const float4 zv = *(const float4*)(z + (size_t)tok * DDIM + 4 * lane);
  float4 q;
  q.x = zv.x + (c.x - zv.x);
  q.y = zv.y + (c.y - zv.y);
  q.z = zv.z + (c.z - zv.z);
  q.w = zv.w + (c.w - zv.w);

  const size_t o = (size_t)tok * DDIM + 4 * lane;
  *(float4*)(out + OUT_ZQ  + o) = q;
  *(float4*)(out + OUT_EMB + o) = c;

  const float dx = q.x - zv.x, dy = q.y - zv.y, dz = q.z - zv.z, dw = q.w - zv.w;
  float s = dx * dx + dy * dy + dz * dz + dw * dw;
  #pragma unroll
  for (int o2 = 32; o2 > 0; o2 >>= 1) s += __shfl_down(s, o2);
  if (lane == 0) {
    atomicAdd(comm, s);
    atomicAdd(&hist[bi], 1.0f);
    out[OUT_IDX + tok] = (float)bi;
  }
}

// ---------------- scalars ----------------
__global__ __launch_bounds__(1024) void k_scal(const float* __restrict__ cu,
                                               const float* __restrict__ hist,
                                               const float* __restrict__ comm,
                                               float* __restrict__ out) {
  __shared__ float red[1024];
  const int tid = threadIdx.x;
  float us[4];
  float s = 0.0f;
  #pragma unroll
  for (int j = 0; j < 4; ++j) {
    const int k = tid * 4 + j;
    us[j] = cu[k] * 0.99f + hist[k];
    s += us[j];
  }
  red[tid] = s; __syncthreads();
  for (int o = 512; o > 0; o >>= 1) {
    if (tid < o) red[tid] += red[tid + o];
    __syncthreads();
  }
  const float usum = red[0];
  __syncthreads();
  float e = 0.0f;
  #pragma unroll
  for (int j = 0; j < 4; ++j) {
    const float p = (usum > 0.0f) ? (us[j] / (usum + GEPS)) : (1.0f / (float)KCB);
    e -= p * logf(p + GEPS);
  }
  red[tid] = e; __syncthreads();
  for (int o = 512; o > 0; o >>= 1) {
    if (tid < o) red[tid] += red[tid + o];
    __syncthreads();
  }
  if (tid == 0) {
    const float entropy = red[0];
    out[OUT_SCAL + 0] = comm[0] / (float)((size_t)NTOK * DDIM);
    out[OUT_SCAL + 1] = expf(entropy);
    out[OUT_SCAL + 2] = entropy;
  }
}

extern "C" void kernel_launch(void* const* d_in, const int* in_sizes, int n_in,
                              void* d_out, int out_size, void* d_ws, size_t ws_size,
                              hipStream_t stream) {
  const float* z  = (const float*)d_in[0];
  const float* u  = (const float*)d_in[1];
  const float* cb = (const float*)d_in[2];
  const float* cu = (const float*)d_in[3];

  float* ws   = (float*)d_ws;
  float* esq  = ws + WS_ESQ;
  float* zsq  = ws + WS_ZSQ;
  float* keyf = ws + WS_KEY;
  unsigned long long* key = (unsigned long long*)keyf;
  float* hist = ws + WS_HIST;
  float* comm = ws + WS_COMM;
  float* out  = (float*)d_out;

  k_prep <<<dim3((KCB + NTOK) / 4), dim3(256), 0, stream>>>(cb, z, esq, zsq, keyf, hist, comm);
  k_score<<<dim3(NTOK / BT, KCB / BK), dim3(256), 0, stream>>>(z, u, cb, esq, zsq, key);
  k_final<<<dim3(NTOK / 4), dim3(256), 0, stream>>>(z, cb, key, out, hist, comm);
  k_scal <<<dim3(1), dim3(1024), 0, stream>>>(cu, hist, comm, out);
}

// Round 5
// 464.779 us; speedup vs baseline: 1.4505x; 1.4505x over previous
//
#include <hip/hip_runtime.h>
#include <math.h>

#define NTOK 8192
#define DDIM 256
#define KCB  4096
#define BT   128     // tokens per block
#define BK   128     // codes per block
#define DC   32      // d-chunk
#define PS   132     // LDS row stride (floats); 528*d bytes keeps 16B alignment
#define GEPS 1e-10f

// ws layout (float units): esq[4096], zsq[8192], key u64[8192], hist[4096], comm[1]
#define WS_ESQ  0
#define WS_ZSQ  (WS_ESQ + KCB)        // 4096
#define WS_KEY  (WS_ZSQ + NTOK)       // 12288 (byte 49152, 8B aligned)
#define WS_HIST (WS_KEY + 2 * NTOK)   // 28672
#define WS_COMM (WS_HIST + KCB)       // 32768 -> ~131 KB total

// out offsets (f32): z_q, embedding, indices, commitment, perplexity, entropy
#define OUT_ZQ   0
#define OUT_EMB  (NTOK * DDIM)
#define OUT_IDX  (2 * NTOK * DDIM)
#define OUT_SCAL (2 * NTOK * DDIM + NTOK)

// ---------------- prep: e_sq, z_sq, zero key/hist/comm ----------------
__global__ __launch_bounds__(256) void k_prep(const float* __restrict__ cb,
                                              const float* __restrict__ z,
                                              float* __restrict__ esq,
                                              float* __restrict__ zsq,
                                              float* __restrict__ keyf,
                                              float* __restrict__ hist,
                                              float* __restrict__ comm) {
  const int lane = threadIdx.x & 63;
  const int wv   = threadIdx.x >> 6;
  const int row  = blockIdx.x * 4 + wv;   // 0..12287
  const float* src = (row < KCB) ? (cb + (size_t)row * DDIM)
                                 : (z  + (size_t)(row - KCB) * DDIM);
  float4 v = *(const float4*)(src + 4 * lane);
  float s = v.x * v.x + v.y * v.y + v.z * v.z + v.w * v.w;
  #pragma unroll
  for (int o = 32; o > 0; o >>= 1) s += __shfl_down(s, o);
  if (lane == 0) {
    if (row < KCB) esq[row] = s;
    else           zsq[row - KCB] = s;
  }
  const int gid = blockIdx.x * 256 + threadIdx.x;
  if (gid < 2 * NTOK) keyf[gid] = 0.0f;
  else if (gid < 2 * NTOK + KCB) hist[gid - 2 * NTOK] = 0.0f;
  else if (gid == 2 * NTOK + KCB) comm[0] = 0.0f;
}

// ---------------- fused distance-GEMM + gumbel + argmax (atomicMax merge) ----------------
// grid (64, 32), block 256. Tile 128 tok x 128 k, thread 8x8, d-chunks of 32.
__global__ __launch_bounds__(256) void k_score(const float* __restrict__ z,
                                               const float* __restrict__ u,
                                               const float* __restrict__ cb,
                                               const float* __restrict__ esq,
                                               const float* __restrict__ zsq,
                                               unsigned long long* __restrict__ key) {
  __shared__ float zsm[DC][PS];   // [d][t]
  __shared__ float csm[DC][PS];   // [d][k]

  const int tid  = threadIdx.x;
  const int tok0 = blockIdx.x * BT;
  const int kb   = blockIdx.y * BK;
  const int tx = tid & 15;        // k sub-tile: 8*tx..8*tx+7
  const int ty = tid >> 4;        // token sub-tile: 8*ty..8*ty+7

  // staging map: each thread owns 4 float4s per chunk: e4 = tid + 256j
  const int srow = tid >> 3;       // 0..31 (+32 per j)
  const int sc4  = (tid & 7) * 4;  // 0,4,..,28

  float acc[8][8] = {};
  float4 zr[4], cr[4];

  // prologue: prefetch chunk 0
  #pragma unroll
  for (int j = 0; j < 4; ++j) {
    const int r = srow + 32 * j;
    zr[j] = *(const float4*)(z  + (size_t)(tok0 + r) * DDIM + sc4);
    cr[j] = *(const float4*)(cb + (size_t)(kb  + r) * DDIM + sc4);
  }

  for (int dc = 0; dc < DDIM / DC; ++dc) {
    __syncthreads();   // previous chunk fully consumed
    #pragma unroll
    for (int j = 0; j < 4; ++j) {
      const int r = srow + 32 * j;
      zsm[sc4 + 0][r] = zr[j].x; zsm[sc4 + 1][r] = zr[j].y;
      zsm[sc4 + 2][r] = zr[j].z; zsm[sc4 + 3][r] = zr[j].w;
      csm[sc4 + 0][r] = cr[j].x; csm[sc4 + 1][r] = cr[j].y;
      csm[sc4 + 2][r] = cr[j].z; csm[sc4 + 3][r] = cr[j].w;
    }
    __syncthreads();

    // prefetch next chunk; global-load latency hides under the 2048 FMAs below
    if (dc + 1 < DDIM / DC) {
      const int d0 = (dc + 1) * DC;
      #pragma unroll
      for (int j = 0; j < 4; ++j) {
        const int r = srow + 32 * j;
        zr[j] = *(const float4*)(z  + (size_t)(tok0 + r) * DDIM + d0 + sc4);
        cr[j] = *(const float4*)(cb + (size_t)(kb  + r) * DDIM + d0 + sc4);
      }
    }

    #pragma unroll 4
    for (int d = 0; d < DC; ++d) {
      const float4 za = *(const float4*)&zsm[d][8 * ty];
      const float4 zb = *(const float4*)&zsm[d][8 * ty + 4];
      const float4 ca = *(const float4*)&csm[d][8 * tx];
      const float4 cc = *(const float4*)&csm[d][8 * tx + 4];
      const float zf[8] = {za.x, za.y, za.z, za.w, zb.x, zb.y, zb.z, zb.w};
      const float cf[8] = {ca.x, ca.y, ca.z, ca.w, cc.x, cc.y, cc.z, cc.w};
      #pragma unroll
      for (int i = 0; i < 8; ++i)
        #pragma unroll
        for (int j = 0; j < 8; ++j) acc[i][j] += zf[i] * cf[j];
    }
  }

  // scores + per-thread argmax (k ascending: strict > keeps lowest k)
  const float4 ea = *(const float4*)(esq + kb + 8 * tx);
  const float4 eb = *(const float4*)(esq + kb + 8 * tx + 4);
  const float esa[8] = {ea.x, ea.y, ea.z, ea.w, eb.x, eb.y, eb.z, eb.w};

  float bv[8];
  int   bj[8];
  #pragma unroll
  for (int i = 0; i < 8; ++i) {
    const int tok = tok0 + 8 * ty + i;
    const float zq = zsq[tok];
    const float4 ua = *(const float4*)(u + (size_t)tok * KCB + kb + 8 * tx);
    const float4 ub = *(const float4*)(u + (size_t)tok * KCB + kb + 8 * tx + 4);
    const float uu[8] = {ua.x, ua.y, ua.z, ua.w, ub.x, ub.y, ub.z, ub.w};
    bv[i] = -3.402823e38f; bj[i] = kb + 8 * tx;
    #pragma unroll
    for (int j = 0; j < 8; ++j) {
      const float g = -logf(-logf(uu[j] + GEPS) + GEPS);
      const float s = -((zq + esa[j]) - 2.0f * acc[i][j]) + g;
      if (s > bv[i]) { bv[i] = s; bj[i] = kb + 8 * tx + j; }
    }
  }

  // block merge across tx groups (overlay zsm/csm), then global atomicMax
  __syncthreads();
  float* pv = &zsm[0][0];          // 128 x 16 floats
  int*   pi = (int*)&csm[0][0];    // 128 x 16 ints
  #pragma unroll
  for (int i = 0; i < 8; ++i) {
    pv[(8 * ty + i) * 16 + tx] = bv[i];
    pi[(8 * ty + i) * 16 + tx] = bj[i];
  }
  __syncthreads();
  if (tid < BT) {
    float best  = pv[tid * 16];
    int   besti = pi[tid * 16];
    for (int x = 1; x < 16; ++x) {   // ascending tx = ascending k
      const float v = pv[tid * 16 + x];
      if (v > best) { best = v; besti = pi[tid * 16 + x]; }
    }
    unsigned int b = __float_as_uint(best);
    b = (b & 0x80000000u) ? ~b : (b | 0x80000000u);   // order-preserving map
    const unsigned long long kk =
        ((unsigned long long)b << 32) | (unsigned int)(KCB - 1 - besti);
    atomicMax(&key[tok0 + tid], kk);
  }
}

// ---------------- finalize per token: decode key, gather, outputs ----------------
__global__ __launch_bounds__(256) void k_final(const float* __restrict__ z,
                                               const float* __restrict__ cb,
                                               const unsigned long long* __restrict__ key,
                                               float* __restrict__ out,
                                               float* __restrict__ hist,
                                               float* __restrict__ comm) {
  const int lane = threadIdx.x & 63;
  const int wv   = threadIdx.x >> 6;
  const int tok  = blockIdx.x * 4 + wv;

  const unsigned long long kk = key[tok];
  int bi = KCB - 1 - (int)(kk & 0xFFFFFFFFu);
  bi = min(max(bi, 0), KCB - 1);

  const float4 c  = *(const float4*)(cb + (size_t)bi * DDIM + 4 * lane);
  const float4 zv = *(const float4*)(z + (size_t)tok * DDIM + 4 * lane);
  float4 q;
  q.x = zv.x + (c.x - zv.x);
  q.y = zv.y + (c.y - zv.y);
  q.z = zv.z + (c.z - zv.z);
  q.w = zv.w + (c.w - zv.w);

  const size_t o = (size_t)tok * DDIM + 4 * lane;
  *(float4*)(out + OUT_ZQ  + o) = q;
  *(float4*)(out + OUT_EMB + o) = c;

  const float dx = q.x - zv.x, dy = q.y - zv.y, dz = q.z - zv.z, dw = q.w - zv.w;
  float s = dx * dx + dy * dy + dz * dz + dw * dw;
  #pragma unroll
  for (int o2 = 32; o2 > 0; o2 >>= 1) s += __shfl_down(s, o2);
  if (lane == 0) {
    atomicAdd(comm, s);
    atomicAdd(&hist[bi], 1.0f);
    out[OUT_IDX + tok] = (float)bi;
  }
}

// ---------------- scalars ----------------
__global__ __launch_bounds__(1024) void k_scal(const float* __restrict__ cu,
                                               const float* __restrict__ hist,
                                               const float* __restrict__ comm,
                                               float* __restrict__ out) {
  __shared__ float red[1024];
  const int tid = threadIdx.x;
  float us[4];
  float s = 0.0f;
  #pragma unroll
  for (int j = 0; j < 4; ++j) {
    const int k = tid * 4 + j;
    us[j] = cu[k] * 0.99f + hist[k];
    s += us[j];
  }
  red[tid] = s; __syncthreads();
  for (int o = 512; o > 0; o >>= 1) {
    if (tid < o) red[tid] += red[tid + o];
    __syncthreads();
  }
  const float usum = red[0];
  __syncthreads();
  float e = 0.0f;
  #pragma unroll
  for (int j = 0; j < 4; ++j) {
    const float p = (usum > 0.0f) ? (us[j] / (usum + GEPS)) : (1.0f / (float)KCB);
    e -= p * logf(p + GEPS);
  }
  red[tid] = e; __syncthreads();
  for (int o = 512; o > 0; o >>= 1) {
    if (tid < o) red[tid] += red[tid + o];
    __syncthreads();
  }
  if (tid == 0) {
    const float entropy = red[0];
    out[OUT_SCAL + 0] = comm[0] / (float)((size_t)NTOK * DDIM);
    out[OUT_SCAL + 1] = expf(entropy);
    out[OUT_SCAL + 2] = entropy;
  }
}

extern "C" void kernel_launch(void* const* d_in, const int* in_sizes, int n_in,
                              void* d_out, int out_size, void* d_ws, size_t ws_size,
                              hipStream_t stream) {
  const float* z  = (const float*)d_in[0];
  const float* u  = (const float*)d_in[1];
  const float* cb = (const float*)d_in[2];
  const float* cu = (const float*)d_in[3];

  float* ws   = (float*)d_ws;
  float* esq  = ws + WS_ESQ;
  float* zsq  = ws + WS_ZSQ;
  float* keyf = ws + WS_KEY;
  unsigned long long* key = (unsigned long long*)keyf;
  float* hist = ws + WS_HIST;
  float* comm = ws + WS_COMM;
  float* out  = (float*)d_out;

  k_prep <<<dim3((KCB + NTOK) / 4), dim3(256), 0, stream>>>(cb, z, esq, zsq, keyf, hist, comm);
  k_score<<<dim3(NTOK / BT, KCB / BK), dim3(256), 0, stream>>>(z, u, cb, esq, zsq, key);
  k_final<<<dim3(NTOK / 4), dim3(256), 0, stream>>>(z, cb, key, out, hist, comm);
  k_scal <<<dim3(1), dim3(1024), 0, stream>>>(cu, hist, comm, out);
}

// Round 6
// 418.321 us; speedup vs baseline: 1.6116x; 1.1111x over previous
//
#include <hip/hip_runtime.h>
#include <math.h>

#define NTOK 8192
#define DDIM 256
#define KCB  4096
#define GEPS 1e-10f

typedef __attribute__((ext_vector_type(8))) short short8;   // 8 bf16 (4 VGPR)
typedef __attribute__((ext_vector_type(4))) float f32x4;

// ws layout (float units)
#define WS_ESQ  0
#define WS_ZSQ  (WS_ESQ + KCB)          // 4096
#define WS_KEY  (WS_ZSQ + NTOK)         // 12288 (u64[8192])
#define WS_HIST (WS_KEY + 2 * NTOK)     // 28672
#define WS_COMM (WS_HIST + KCB)         // 32768
#define WS_ZH   32776                   // 16B-aligned; each z plane = 1048576 floats (4MB)
#define WS_ZM   (WS_ZH + NTOK * DDIM / 2)
#define WS_ZL   (WS_ZM + NTOK * DDIM / 2)
#define WS_CH   (WS_ZL + NTOK * DDIM / 2)   // cb planes = 524288 floats (2MB)
#define WS_CM   (WS_CH + KCB * DDIM / 2)
#define WS_CL   (WS_CM + KCB * DDIM / 2)
#define WS_END  (WS_CL + KCB * DDIM / 2)    // 4751368 floats ≈ 19.01 MB

// out offsets (f32): z_q, embedding, indices, commitment, perplexity, entropy
#define OUT_ZQ   0
#define OUT_EMB  (NTOK * DDIM)
#define OUT_IDX  (2 * NTOK * DDIM)
#define OUT_SCAL (2 * NTOK * DDIM + NTOK)

__device__ __forceinline__ unsigned short f2bf(float x) {   // RNE truncate f32->bf16
  unsigned int u = __float_as_uint(x);
  u += 0x7FFFu + ((u >> 16) & 1u);
  return (unsigned short)(u >> 16);
}
__device__ __forceinline__ float bf2f(unsigned short h) {
  return __uint_as_float(((unsigned int)h) << 16);
}

// ---------------- prep: e_sq, z_sq, zero key/hist/comm ----------------
__global__ __launch_bounds__(256) void k_prep(const float* __restrict__ cb,
                                              const float* __restrict__ z,
                                              float* __restrict__ esq,
                                              float* __restrict__ zsq,
                                              float* __restrict__ keyf,
                                              float* __restrict__ hist,
                                              float* __restrict__ comm) {
  const int lane = threadIdx.x & 63;
  const int wv   = threadIdx.x >> 6;
  const int row  = blockIdx.x * 4 + wv;   // 0..12287
  const float* src = (row < KCB) ? (cb + (size_t)row * DDIM)
                                 : (z  + (size_t)(row - KCB) * DDIM);
  float4 v = *(const float4*)(src + 4 * lane);
  float s = v.x * v.x + v.y * v.y + v.z * v.z + v.w * v.w;
  #pragma unroll
  for (int o = 32; o > 0; o >>= 1) s += __shfl_down(s, o);
  if (lane == 0) {
    if (row < KCB) esq[row] = s;
    else           zsq[row - KCB] = s;
  }
  const int gid = blockIdx.x * 256 + threadIdx.x;
  if (gid < 2 * NTOK) keyf[gid] = 0.0f;
  else if (gid < 2 * NTOK + KCB) hist[gid - 2 * NTOK] = 0.0f;
  else if (gid == 2 * NTOK + KCB) comm[0] = 0.0f;
}

// ---------------- split f32 -> 3 bf16 planes (z and cb) ----------------
__global__ __launch_bounds__(256) void k_planes(const float* __restrict__ z,
                                                const float* __restrict__ cb,
                                                unsigned short* __restrict__ zh,
                                                unsigned short* __restrict__ zm,
                                                unsigned short* __restrict__ zl,
                                                unsigned short* __restrict__ ch,
                                                unsigned short* __restrict__ cm,
                                                unsigned short* __restrict__ cl) {
  const int idx = blockIdx.x * 256 + threadIdx.x;      // float4 index
  const int nz4 = NTOK * DDIM / 4;
  const bool isz = idx < nz4;
  const float4 v = isz ? ((const float4*)z)[idx] : ((const float4*)cb)[idx - nz4];
  const float vv[4] = {v.x, v.y, v.z, v.w};
  ushort4 h4, m4, l4;
  unsigned short* hp = (unsigned short*)&h4;
  unsigned short* mp = (unsigned short*)&m4;
  unsigned short* lp = (unsigned short*)&l4;
  #pragma unroll
  for (int j = 0; j < 4; ++j) {
    const float x  = vv[j];
    const unsigned short h = f2bf(x);
    const float r1 = x - bf2f(h);
    const unsigned short m = f2bf(r1);
    const float r2 = r1 - bf2f(m);
    hp[j] = h; mp[j] = m; lp[j] = f2bf(r2);
  }
  if (isz) {
    ((ushort4*)zh)[idx] = h4; ((ushort4*)zm)[idx] = m4; ((ushort4*)zl)[idx] = l4;
  } else {
    const int o = idx - nz4;
    ((ushort4*)ch)[o] = h4; ((ushort4*)cm)[o] = m4; ((ushort4*)cl)[o] = l4;
  }
}

// ---------------- MFMA split-bf16 distance GEMM + gumbel + argmax ----------------
// grid (KCB/128, NTOK/64), block 256 = 4 waves (2x2 wave tile of 32tok x 64code).
// Fragments loaded straight from global planes (L2/L3 resident). No LDS.
__global__ __launch_bounds__(256) void k_mfma(const unsigned short* __restrict__ zh,
                                              const unsigned short* __restrict__ zm,
                                              const unsigned short* __restrict__ zl,
                                              const unsigned short* __restrict__ ch,
                                              const unsigned short* __restrict__ cm,
                                              const unsigned short* __restrict__ cl,
                                              const float* __restrict__ u,
                                              const float* __restrict__ esq,
                                              const float* __restrict__ zsq,
                                              unsigned long long* __restrict__ key) {
  const int tid = threadIdx.x;
  const int l   = tid & 63;
  const int wid = tid >> 6;
  const int wm  = wid & 1;        // token half
  const int wn  = wid >> 1;       // code half
  const int tok0 = blockIdx.y * 64 + wm * 32;
  const int c0   = blockIdx.x * 128 + wn * 64;

  const int lrow = l & 15;
  const int lk   = (l >> 4) * 8;   // k-offset within 32-wide K step

  // A: lane holds token row (l&15), 8 contiguous d at lk.  B: same for code rows.
  size_t aoff[2], boff[4];
  #pragma unroll
  for (int mi = 0; mi < 2; ++mi) aoff[mi] = (size_t)(tok0 + mi * 16 + lrow) * DDIM + lk;
  #pragma unroll
  for (int ni = 0; ni < 4; ++ni) boff[ni] = (size_t)(c0 + ni * 16 + lrow) * DDIM + lk;

  f32x4 acc[2][4] = {};

  #pragma unroll 1
  for (int k = 0; k < DDIM; k += 32) {
    short8 ah[2], am[2], al[2], bh[4], bm[4], bl[4];
    #pragma unroll
    for (int mi = 0; mi < 2; ++mi) {
      ah[mi] = *(const short8*)(zh + aoff[mi] + k);
      am[mi] = *(const short8*)(zm + aoff[mi] + k);
      al[mi] = *(const short8*)(zl + aoff[mi] + k);
    }
    #pragma unroll
    for (int ni = 0; ni < 4; ++ni) {
      bh[ni] = *(const short8*)(ch + boff[ni] + k);
      bm[ni] = *(const short8*)(cm + boff[ni] + k);
      bl[ni] = *(const short8*)(cl + boff[ni] + k);
    }
    #pragma unroll
    for (int mi = 0; mi < 2; ++mi)
      #pragma unroll
      for (int ni = 0; ni < 4; ++ni) {
        f32x4 a = acc[mi][ni];
        a = __builtin_amdgcn_mfma_f32_16x16x32_bf16(am[mi], bm[ni], a, 0, 0, 0);
        a = __builtin_amdgcn_mfma_f32_16x16x32_bf16(ah[mi], bl[ni], a, 0, 0, 0);
        a = __builtin_amdgcn_mfma_f32_16x16x32_bf16(al[mi], bh[ni], a, 0, 0, 0);
        a = __builtin_amdgcn_mfma_f32_16x16x32_bf16(ah[mi], bm[ni], a, 0, 0, 0);
        a = __builtin_amdgcn_mfma_f32_16x16x32_bf16(am[mi], bh[ni], a, 0, 0, 0);
        a = __builtin_amdgcn_mfma_f32_16x16x32_bf16(ah[mi], bh[ni], a, 0, 0, 0);
        acc[mi][ni] = a;
      }
  }

  // epilogue: score + per-token argmax. C/D layout (m89): col=l&15, row=(l>>4)*4+reg.
  float esv[4];
  #pragma unroll
  for (int ni = 0; ni < 4; ++ni) esv[ni] = esq[c0 + ni * 16 + lrow];
  const int rbase = (l >> 4) * 4;

  #pragma unroll
  for (int mi = 0; mi < 2; ++mi) {
    #pragma unroll
    for (int r = 0; r < 4; ++r) {
      const int t  = tok0 + mi * 16 + rbase + r;
      const float zq = zsq[t];
      float bv = -3.402823e38f;
      int   bc = c0 + lrow;
      #pragma unroll
      for (int ni = 0; ni < 4; ++ni) {
        const int c = c0 + ni * 16 + lrow;
        const float uu = u[(size_t)t * KCB + c];
        const float g  = -logf(-logf(uu + GEPS) + GEPS);
        const float s  = -((zq + esv[ni]) - 2.0f * acc[mi][ni][r]) + g;
        if (s > bv) { bv = s; bc = c; }          // ni ascending = code ascending
      }
      // reduce across the 16 lanes sharing rbase (xor within 16-group)
      #pragma unroll
      for (int m = 1; m < 16; m <<= 1) {
        const float ov = __shfl_xor(bv, m);
        const int   oc = __shfl_xor(bc, m);
        if (ov > bv || (ov == bv && oc < bc)) { bv = ov; bc = oc; }
      }
      if (lrow == 0) {
        unsigned int b = __float_as_uint(bv);
        b = (b & 0x80000000u) ? ~b : (b | 0x80000000u);
        const unsigned long long kk =
            ((unsigned long long)b << 32) | (unsigned int)(KCB - 1 - bc);
        atomicMax(&key[t], kk);
      }
    }
  }
}

// ---------------- fallback f32 path (round-5 kernel, used if ws too small) ----------------
#define BT 128
#define BK 128
#define DC 32
#define PS 132
__global__ __launch_bounds__(256) void k_score(const float* __restrict__ z,
                                               const float* __restrict__ u,
                                               const float* __restrict__ cb,
                                               const float* __restrict__ esq,
                                               const float* __restrict__ zsq,
                                               unsigned long long* __restrict__ key) {
  __shared__ float zsm[DC][PS];
  __shared__ float csm[DC][PS];
  const int tid  = threadIdx.x;
  const int tok0 = blockIdx.x * BT;
  const int kb   = blockIdx.y * BK;
  const int tx = tid & 15;
  const int ty = tid >> 4;
  const int srow = tid >> 3;
  const int sc4  = (tid & 7) * 4;
  float acc[8][8] = {};
  float4 zr[4], cr[4];
  #pragma unroll
  for (int j = 0; j < 4; ++j) {
    const int r = srow + 32 * j;
    zr[j] = *(const float4*)(z  + (size_t)(tok0 + r) * DDIM + sc4);
    cr[j] = *(const float4*)(cb + (size_t)(kb  + r) * DDIM + sc4);
  }
  for (int dc = 0; dc < DDIM / DC; ++dc) {
    __syncthreads();
    #pragma unroll
    for (int j = 0; j < 4; ++j) {
      const int r = srow + 32 * j;
      zsm[sc4 + 0][r] = zr[j].x; zsm[sc4 + 1][r] = zr[j].y;
      zsm[sc4 + 2][r] = zr[j].z; zsm[sc4 + 3][r] = zr[j].w;
      csm[sc4 + 0][r] = cr[j].x; csm[sc4 + 1][r] = cr[j].y;
      csm[sc4 + 2][r] = cr[j].z; csm[sc4 + 3][r] = cr[j].w;
    }
    __syncthreads();
    if (dc + 1 < DDIM / DC) {
      const int d0 = (dc + 1) * DC;
      #pragma unroll
      for (int j = 0; j < 4; ++j) {
        const int r = srow + 32 * j;
        zr[j] = *(const float4*)(z  + (size_t)(tok0 + r) * DDIM + d0 + sc4);
        cr[j] = *(const float4*)(cb + (size_t)(kb  + r) * DDIM + d0 + sc4);
      }
    }
    #pragma unroll 4
    for (int d = 0; d < DC; ++d) {
      const float4 za = *(const float4*)&zsm[d][8 * ty];
      const float4 zb = *(const float4*)&zsm[d][8 * ty + 4];
      const float4 ca = *(const float4*)&csm[d][8 * tx];
      const float4 cc = *(const float4*)&csm[d][8 * tx + 4];
      const float zf[8] = {za.x, za.y, za.z, za.w, zb.x, zb.y, zb.z, zb.w};
      const float cf[8] = {ca.x, ca.y, ca.z, ca.w, cc.x, cc.y, cc.z, cc.w};
      #pragma unroll
      for (int i = 0; i < 8; ++i)
        #pragma unroll
        for (int j = 0; j < 8; ++j) acc[i][j] += zf[i] * cf[j];
    }
  }
  const float4 ea = *(const float4*)(esq + kb + 8 * tx);
  const float4 eb = *(const float4*)(esq + kb + 8 * tx + 4);
  const float esa[8] = {ea.x, ea.y, ea.z, ea.w, eb.x, eb.y, eb.z, eb.w};
  float bv[8]; int bj[8];
  #pragma unroll
  for (int i = 0; i < 8; ++i) {
    const int tok = tok0 + 8 * ty + i;
    const float zq = zsq[tok];
    const float4 ua = *(const float4*)(u + (size_t)tok * KCB + kb + 8 * tx);
    const float4 ub = *(const float4*)(u + (size_t)tok * KCB + kb + 8 * tx + 4);
    const float uu[8] = {ua.x, ua.y, ua.z, ua.w, ub.x, ub.y, ub.z, ub.w};
    bv[i] = -3.402823e38f; bj[i] = kb + 8 * tx;
    #pragma unroll
    for (int j = 0; j < 8; ++j) {
      const float g = -logf(-logf(uu[j] + GEPS) + GEPS);
      const float s = -((zq + esa[j]) - 2.0f * acc[i][j]) + g;
      if (s > bv[i]) { bv[i] = s; bj[i] = kb + 8 * tx + j; }
    }
  }
  __syncthreads();
  float* pv = &zsm[0][0];
  int*   pi = (int*)&csm[0][0];
  #pragma unroll
  for (int i = 0; i < 8; ++i) {
    pv[(8 * ty + i) * 16 + tx] = bv[i];
    pi[(8 * ty + i) * 16 + tx] = bj[i];
  }
  __syncthreads();
  if (tid < BT) {
    float best  = pv[tid * 16];
    int   besti = pi[tid * 16];
    for (int x = 1; x < 16; ++x) {
      const float v = pv[tid * 16 + x];
      if (v > best) { best = v; besti = pi[tid * 16 + x]; }
    }
    unsigned int b = __float_as_uint(best);
    b = (b & 0x80000000u) ? ~b : (b | 0x80000000u);
    const unsigned long long kk =
        ((unsigned long long)b << 32) | (unsigned int)(KCB - 1 - besti);
    atomicMax(&key[tok0 + tid], kk);
  }
}

// ---------------- finalize per token ----------------
__global__ __launch_bounds__(256) void k_final(const float* __restrict__ z,
                                               const float* __restrict__ cb,
                                               const unsigned long long* __restrict__ key,
                                               float* __restrict__ out,
                                               float* __restrict__ hist,
                                               float* __restrict__ comm) {
  const int lane = threadIdx.x & 63;
  const int wv   = threadIdx.x >> 6;
  const int tok  = blockIdx.x * 4 + wv;
  const unsigned long long kk = key[tok];
  int bi = KCB - 1 - (int)(kk & 0xFFFFFFFFu);
  bi = min(max(bi, 0), KCB - 1);
  const float4 c  = *(const float4*)(cb + (size_t)bi * DDIM + 4 * lane);
  const float4 zv = *(const float4*)(z + (size_t)tok * DDIM + 4 * lane);
  float4 q;
  q.x = zv.x + (c.x - zv.x);
  q.y = zv.y + (c.y - zv.y);
  q.z = zv.z + (c.z - zv.z);
  q.w = zv.w + (c.w - zv.w);
  const size_t o = (size_t)tok * DDIM + 4 * lane;
  *(float4*)(out + OUT_ZQ  + o) = q;
  *(float4*)(out + OUT_EMB + o) = c;
  const float dx = q.x - zv.x, dy = q.y - zv.y, dz = q.z - zv.z, dw = q.w - zv.w;
  float s = dx * dx + dy * dy + dz * dz + dw * dw;
  #pragma unroll
  for (int o2 = 32; o2 > 0; o2 >>= 1) s += __shfl_down(s, o2);
  if (lane == 0) {
    atomicAdd(comm, s);
    atomicAdd(&hist[bi], 1.0f);
    out[OUT_IDX + tok] = (float)bi;
  }
}

// ---------------- scalars ----------------
__global__ __launch_bounds__(1024) void k_scal(const float* __restrict__ cu,
                                               const float* __restrict__ hist,
                                               const float* __restrict__ comm,
                                               float* __restrict__ out) {
  __shared__ float red[1024];
  const int tid = threadIdx.x;
  float us[4];
  float s = 0.0f;
  #pragma unroll
  for (int j = 0; j < 4; ++j) {
    const int k = tid * 4 + j;
    us[j] = cu[k] * 0.99f + hist[k];
    s += us[j];
  }
  red[tid] = s; __syncthreads();
  for (int o = 512; o > 0; o >>= 1) {
    if (tid < o) red[tid] += red[tid + o];
    __syncthreads();
  }
  const float usum = red[0];
  __syncthreads();
  float e = 0.0f;
  #pragma unroll
  for (int j = 0; j < 4; ++j) {
    const float p = (usum > 0.0f) ? (us[j] / (usum + GEPS)) : (1.0f / (float)KCB);
    e -= p * logf(p + GEPS);
  }
  red[tid] = e; __syncthreads();
  for (int o = 512; o > 0; o >>= 1) {
    if (tid < o) red[tid] += red[tid + o];
    __syncthreads();
  }
  if (tid == 0) {
    const float entropy = red[0];
    out[OUT_SCAL + 0] = comm[0] / (float)((size_t)NTOK * DDIM);
    out[OUT_SCAL + 1] = expf(entropy);
    out[OUT_SCAL + 2] = entropy;
  }
}

extern "C" void kernel_launch(void* const* d_in, const int* in_sizes, int n_in,
                              void* d_out, int out_size, void* d_ws, size_t ws_size,
                              hipStream_t stream) {
  const float* z  = (const float*)d_in[0];
  const float* u  = (const float*)d_in[1];
  const float* cb = (const float*)d_in[2];
  const float* cu = (const float*)d_in[3];

  float* ws   = (float*)d_ws;
  float* esq  = ws + WS_ESQ;
  float* zsq  = ws + WS_ZSQ;
  float* keyf = ws + WS_KEY;
  unsigned long long* key = (unsigned long long*)keyf;
  float* hist = ws + WS_HIST;
  float* comm = ws + WS_COMM;
  float* out  = (float*)d_out;

  k_prep<<<dim3((KCB + NTOK) / 4), dim3(256), 0, stream>>>(cb, z, esq, zsq, keyf, hist, comm);

  if (ws_size >= (size_t)WS_END * 4) {
    unsigned short* zh = (unsigned short*)(ws + WS_ZH);
    unsigned short* zm = (unsigned short*)(ws + WS_ZM);
    unsigned short* zl = (unsigned short*)(ws + WS_ZL);
    unsigned short* ch = (unsigned short*)(ws + WS_CH);
    unsigned short* cm = (unsigned short*)(ws + WS_CM);
    unsigned short* cl = (unsigned short*)(ws + WS_CL);
    k_planes<<<dim3((NTOK + KCB) * DDIM / 4 / 256), dim3(256), 0, stream>>>(
        z, cb, zh, zm, zl, ch, cm, cl);
    k_mfma<<<dim3(KCB / 128, NTOK / 64), dim3(256), 0, stream>>>(
        zh, zm, zl, ch, cm, cl, u, esq, zsq, key);
  } else {
    k_score<<<dim3(NTOK / BT, KCB / BK), dim3(256), 0, stream>>>(z, u, cb, esq, zsq, key);
  }

  k_final<<<dim3(NTOK / 4), dim3(256), 0, stream>>>(z, cb, key, out, hist, comm);
  k_scal <<<dim3(1), dim3(1024), 0, stream>>>(cu, hist, comm, out);
}

// Round 7
// 404.070 us; speedup vs baseline: 1.6684x; 1.0353x over previous
//
#include <hip/hip_runtime.h>
#include <math.h>

#define NTOK 8192
#define DDIM 256
#define KCB  4096
#define GEPS 1e-10f

typedef __attribute__((ext_vector_type(8))) short short8;   // 8 bf16 (4 VGPR)
typedef __attribute__((ext_vector_type(4))) float f32x4;

// ws layout (float units)
#define WS_ESQ  0
#define WS_ZSQ  (WS_ESQ + KCB)          // 4096
#define WS_KEY  (WS_ZSQ + NTOK)         // 12288 (u64[8192])
#define WS_HIST (WS_KEY + 2 * NTOK)     // 28672
#define WS_COMM (WS_HIST + KCB)         // 32768
#define WS_ZH   32776                   // 16B-aligned; z planes 1048576 floats-worth/2
#define WS_ZM   (WS_ZH + NTOK * DDIM / 2)
#define WS_ZL   (WS_ZM + NTOK * DDIM / 2)
#define WS_CH   (WS_ZL + NTOK * DDIM / 2)
#define WS_CM   (WS_CH + KCB * DDIM / 2)
#define WS_CL   (WS_CM + KCB * DDIM / 2)
#define WS_END  (WS_CL + KCB * DDIM / 2)    // ≈ 19.01 MB

// out offsets (f32): z_q, embedding, indices, commitment, perplexity, entropy
#define OUT_ZQ   0
#define OUT_EMB  (NTOK * DDIM)
#define OUT_IDX  (2 * NTOK * DDIM)
#define OUT_SCAL (2 * NTOK * DDIM + NTOK)

__device__ __forceinline__ unsigned short f2bf(float x) {   // RNE f32->bf16
  unsigned int u = __float_as_uint(x);
  u += 0x7FFFu + ((u >> 16) & 1u);
  return (unsigned short)(u >> 16);
}
__device__ __forceinline__ float bf2f(unsigned short h) {
  return __uint_as_float(((unsigned int)h) << 16);
}

// ---------------- prep ----------------
__global__ __launch_bounds__(256) void k_prep(const float* __restrict__ cb,
                                              const float* __restrict__ z,
                                              float* __restrict__ esq,
                                              float* __restrict__ zsq,
                                              float* __restrict__ keyf,
                                              float* __restrict__ hist,
                                              float* __restrict__ comm) {
  const int lane = threadIdx.x & 63;
  const int wv   = threadIdx.x >> 6;
  const int row  = blockIdx.x * 4 + wv;   // 0..12287
  const float* src = (row < KCB) ? (cb + (size_t)row * DDIM)
                                 : (z  + (size_t)(row - KCB) * DDIM);
  float4 v = *(const float4*)(src + 4 * lane);
  float s = v.x * v.x + v.y * v.y + v.z * v.z + v.w * v.w;
  #pragma unroll
  for (int o = 32; o > 0; o >>= 1) s += __shfl_down(s, o);
  if (lane == 0) {
    if (row < KCB) esq[row] = s;
    else           zsq[row - KCB] = s;
  }
  const int gid = blockIdx.x * 256 + threadIdx.x;
  if (gid < 2 * NTOK) keyf[gid] = 0.0f;
  else if (gid < 2 * NTOK + KCB) hist[gid - 2 * NTOK] = 0.0f;
  else if (gid == 2 * NTOK + KCB) comm[0] = 0.0f;
}

// ---------------- split f32 -> 3 bf16 planes ----------------
__global__ __launch_bounds__(256) void k_planes(const float* __restrict__ z,
                                                const float* __restrict__ cb,
                                                unsigned short* __restrict__ zh,
                                                unsigned short* __restrict__ zm,
                                                unsigned short* __restrict__ zl,
                                                unsigned short* __restrict__ ch,
                                                unsigned short* __restrict__ cm,
                                                unsigned short* __restrict__ cl) {
  const int idx = blockIdx.x * 256 + threadIdx.x;      // float4 index
  const int nz4 = NTOK * DDIM / 4;
  const bool isz = idx < nz4;
  const float4 v = isz ? ((const float4*)z)[idx] : ((const float4*)cb)[idx - nz4];
  const float vv[4] = {v.x, v.y, v.z, v.w};
  ushort4 h4, m4, l4;
  unsigned short* hp = (unsigned short*)&h4;
  unsigned short* mp = (unsigned short*)&m4;
  unsigned short* lp = (unsigned short*)&l4;
  #pragma unroll
  for (int j = 0; j < 4; ++j) {
    const float x  = vv[j];
    const unsigned short h = f2bf(x);
    const float r1 = x - bf2f(h);
    const unsigned short m = f2bf(r1);
    const float r2 = r1 - bf2f(m);
    hp[j] = h; mp[j] = m; lp[j] = f2bf(r2);
  }
  if (isz) {
    ((ushort4*)zh)[idx] = h4; ((ushort4*)zm)[idx] = m4; ((ushort4*)zl)[idx] = l4;
  } else {
    const int o = idx - nz4;
    ((ushort4*)ch)[o] = h4; ((ushort4*)cm)[o] = m4; ((ushort4*)cl)[o] = l4;
  }
}

// ---------------- MFMA split-bf16 GEMM, 2-deep register pipeline ----------------
struct Frag {
  short8 ah[2], am[2], al[2];
  short8 bh[4], bm[4], bl[4];
};

__device__ __forceinline__ void load_frag(Frag& f,
    const unsigned short* __restrict__ zh, const unsigned short* __restrict__ zm,
    const unsigned short* __restrict__ zl, const unsigned short* __restrict__ ch,
    const unsigned short* __restrict__ cm, const unsigned short* __restrict__ cl,
    const unsigned int* aoff, const unsigned int* boff, int k) {
  #pragma unroll
  for (int mi = 0; mi < 2; ++mi) {
    f.ah[mi] = *(const short8*)(zh + aoff[mi] + k);
    f.am[mi] = *(const short8*)(zm + aoff[mi] + k);
    f.al[mi] = *(const short8*)(zl + aoff[mi] + k);
  }
  #pragma unroll
  for (int ni = 0; ni < 4; ++ni) {
    f.bh[ni] = *(const short8*)(ch + boff[ni] + k);
    f.bm[ni] = *(const short8*)(cm + boff[ni] + k);
    f.bl[ni] = *(const short8*)(cl + boff[ni] + k);
  }
}

__device__ __forceinline__ void mfma_frag(const Frag& f, f32x4 acc[2][4]) {
  #pragma unroll
  for (int mi = 0; mi < 2; ++mi)
    #pragma unroll
    for (int ni = 0; ni < 4; ++ni) {
      f32x4 a = acc[mi][ni];
      a = __builtin_amdgcn_mfma_f32_16x16x32_bf16(f.am[mi], f.bm[ni], a, 0, 0, 0);
      a = __builtin_amdgcn_mfma_f32_16x16x32_bf16(f.ah[mi], f.bl[ni], a, 0, 0, 0);
      a = __builtin_amdgcn_mfma_f32_16x16x32_bf16(f.al[mi], f.bh[ni], a, 0, 0, 0);
      a = __builtin_amdgcn_mfma_f32_16x16x32_bf16(f.ah[mi], f.bm[ni], a, 0, 0, 0);
      a = __builtin_amdgcn_mfma_f32_16x16x32_bf16(f.am[mi], f.bh[ni], a, 0, 0, 0);
      a = __builtin_amdgcn_mfma_f32_16x16x32_bf16(f.ah[mi], f.bh[ni], a, 0, 0, 0);
      acc[mi][ni] = a;
    }
}

// grid (KCB/128, NTOK/64), block 256 = 4 waves (2 tok-halves x 2 code-halves).
__global__ __launch_bounds__(256) void k_mfma(const unsigned short* __restrict__ zh,
                                              const unsigned short* __restrict__ zm,
                                              const unsigned short* __restrict__ zl,
                                              const unsigned short* __restrict__ ch,
                                              const unsigned short* __restrict__ cm,
                                              const unsigned short* __restrict__ cl,
                                              const float* __restrict__ u,
                                              const float* __restrict__ esq,
                                              const float* __restrict__ zsq,
                                              unsigned long long* __restrict__ key) {
  const int tid = threadIdx.x;
  const int l   = tid & 63;
  const int wid = tid >> 6;
  const int wm  = wid & 1;
  const int wn  = wid >> 1;
  const int tok0 = blockIdx.y * 64 + wm * 32;
  const int c0   = blockIdx.x * 128 + wn * 64;

  const int lrow = l & 15;
  const int lk   = (l >> 4) * 8;

  unsigned int aoff[2], boff[4];
  #pragma unroll
  for (int mi = 0; mi < 2; ++mi) aoff[mi] = (unsigned)(tok0 + mi * 16 + lrow) * DDIM + lk;
  #pragma unroll
  for (int ni = 0; ni < 4; ++ni) boff[ni] = (unsigned)(c0 + ni * 16 + lrow) * DDIM + lk;

  f32x4 acc[2][4] = {};
  Frag f0, f1;

  // 2-deep pipeline over 8 K-steps (k += 32), fully unrolled, static indices
  load_frag(f0, zh, zm, zl, ch, cm, cl, aoff, boff, 0);
  load_frag(f1, zh, zm, zl, ch, cm, cl, aoff, boff, 32);
  mfma_frag(f0, acc);
  load_frag(f0, zh, zm, zl, ch, cm, cl, aoff, boff, 64);
  mfma_frag(f1, acc);
  load_frag(f1, zh, zm, zl, ch, cm, cl, aoff, boff, 96);
  mfma_frag(f0, acc);
  load_frag(f0, zh, zm, zl, ch, cm, cl, aoff, boff, 128);
  mfma_frag(f1, acc);
  load_frag(f1, zh, zm, zl, ch, cm, cl, aoff, boff, 160);
  mfma_frag(f0, acc);
  load_frag(f0, zh, zm, zl, ch, cm, cl, aoff, boff, 192);
  mfma_frag(f1, acc);
  load_frag(f1, zh, zm, zl, ch, cm, cl, aoff, boff, 224);
  mfma_frag(f0, acc);
  mfma_frag(f1, acc);

  // epilogue: score + argmax. C/D layout: col=l&15, row=(l>>4)*4+reg (m89-verified).
  float esv[4];
  #pragma unroll
  for (int ni = 0; ni < 4; ++ni) esv[ni] = esq[c0 + ni * 16 + lrow];
  const int rbase = (l >> 4) * 4;

  #pragma unroll
  for (int mi = 0; mi < 2; ++mi) {
    #pragma unroll
    for (int r = 0; r < 4; ++r) {
      const int t  = tok0 + mi * 16 + rbase + r;
      const float zq = zsq[t];
      float bv = -3.402823e38f;
      int   bc = c0 + lrow;
      #pragma unroll
      for (int ni = 0; ni < 4; ++ni) {
        const int c = c0 + ni * 16 + lrow;
        const float uu = u[(size_t)t * KCB + c];
        const float g  = -logf(-logf(uu + GEPS) + GEPS);
        const float s  = -((zq + esv[ni]) - 2.0f * acc[mi][ni][r]) + g;
        if (s > bv) { bv = s; bc = c; }
      }
      #pragma unroll
      for (int m = 1; m < 16; m <<= 1) {
        const float ov = __shfl_xor(bv, m);
        const int   oc = __shfl_xor(bc, m);
        if (ov > bv || (ov == bv && oc < bc)) { bv = ov; bc = oc; }
      }
      if (lrow == 0) {
        unsigned int b = __float_as_uint(bv);
        b = (b & 0x80000000u) ? ~b : (b | 0x80000000u);
        const unsigned long long kk =
            ((unsigned long long)b << 32) | (unsigned int)(KCB - 1 - bc);
        atomicMax(&key[t], kk);
      }
    }
  }
}

// ---------------- fallback f32 path (used only if ws too small) ----------------
#define BT 128
#define BK 128
#define DC 32
#define PS 132
__global__ __launch_bounds__(256) void k_score(const float* __restrict__ z,
                                               const float* __restrict__ u,
                                               const float* __restrict__ cb,
                                               const float* __restrict__ esq,
                                               const float* __restrict__ zsq,
                                               unsigned long long* __restrict__ key) {
  __shared__ float zsm[DC][PS];
  __shared__ float csm[DC][PS];
  const int tid  = threadIdx.x;
  const int tok0 = blockIdx.x * BT;
  const int kb   = blockIdx.y * BK;
  const int tx = tid & 15;
  const int ty = tid >> 4;
  const int srow = tid >> 3;
  const int sc4  = (tid & 7) * 4;
  float acc[8][8] = {};
  float4 zr[4], cr[4];
  #pragma unroll
  for (int j = 0; j < 4; ++j) {
    const int r = srow + 32 * j;
    zr[j] = *(const float4*)(z  + (size_t)(tok0 + r) * DDIM + sc4);
    cr[j] = *(const float4*)(cb + (size_t)(kb  + r) * DDIM + sc4);
  }
  for (int dc = 0; dc < DDIM / DC; ++dc) {
    __syncthreads();
    #pragma unroll
    for (int j = 0; j < 4; ++j) {
      const int r = srow + 32 * j;
      zsm[sc4 + 0][r] = zr[j].x; zsm[sc4 + 1][r] = zr[j].y;
      zsm[sc4 + 2][r] = zr[j].z; zsm[sc4 + 3][r] = zr[j].w;
      csm[sc4 + 0][r] = cr[j].x; csm[sc4 + 1][r] = cr[j].y;
      csm[sc4 + 2][r] = cr[j].z; csm[sc4 + 3][r] = cr[j].w;
    }
    __syncthreads();
    if (dc + 1 < DDIM / DC) {
      const int d0 = (dc + 1) * DC;
      #pragma unroll
      for (int j = 0; j < 4; ++j) {
        const int r = srow + 32 * j;
        zr[j] = *(const float4*)(z  + (size_t)(tok0 + r) * DDIM + d0 + sc4);
        cr[j] = *(const float4*)(cb + (size_t)(kb  + r) * DDIM + d0 + sc4);
      }
    }
    #pragma unroll 4
    for (int d = 0; d < DC; ++d) {
      const float4 za = *(const float4*)&zsm[d][8 * ty];
      const float4 zb = *(const float4*)&zsm[d][8 * ty + 4];
      const float4 ca = *(const float4*)&csm[d][8 * tx];
      const float4 cc = *(const float4*)&csm[d][8 * tx + 4];
      const float zf[8] = {za.x, za.y, za.z, za.w, zb.x, zb.y, zb.z, zb.w};
      const float cf[8] = {ca.x, ca.y, ca.z, ca.w, cc.x, cc.y, cc.z, cc.w};
      #pragma unroll
      for (int i = 0; i < 8; ++i)
        #pragma unroll
        for (int j = 0; j < 8; ++j) acc[i][j] += zf[i] * cf[j];
    }
  }
  const float4 ea = *(const float4*)(esq + kb + 8 * tx);
  const float4 eb = *(const float4*)(esq + kb + 8 * tx + 4);
  const float esa[8] = {ea.x, ea.y, ea.z, ea.w, eb.x, eb.y, eb.z, eb.w};
  float bv[8]; int bj[8];
  #pragma unroll
  for (int i = 0; i < 8; ++i) {
    const int tok = tok0 + 8 * ty + i;
    const float zq = zsq[tok];
    const float4 ua = *(const float4*)(u + (size_t)tok * KCB + kb + 8 * tx);
    const float4 ub = *(const float4*)(u + (size_t)tok * KCB + kb + 8 * tx + 4);
    const float uu[8] = {ua.x, ua.y, ua.z, ua.w, ub.x, ub.y, ub.z, ub.w};
    bv[i] = -3.402823e38f; bj[i] = kb + 8 * tx;
    #pragma unroll
    for (int j = 0; j < 8; ++j) {
      const float g = -logf(-logf(uu[j] + GEPS) + GEPS);
      const float s = -((zq + esa[j]) - 2.0f * acc[i][j]) + g;
      if (s > bv[i]) { bv[i] = s; bj[i] = kb + 8 * tx + j; }
    }
  }
  __syncthreads();
  float* pv = &zsm[0][0];
  int*   pi = (int*)&csm[0][0];
  #pragma unroll
  for (int i = 0; i < 8; ++i) {
    pv[(8 * ty + i) * 16 + tx] = bv[i];
    pi[(8 * ty + i) * 16 + tx] = bj[i];
  }
  __syncthreads();
  if (tid < BT) {
    float best  = pv[tid * 16];
    int   besti = pi[tid * 16];
    for (int x = 1; x < 16; ++x) {
      const float v = pv[tid * 16 + x];
      if (v > best) { best = v; besti = pi[tid * 16 + x]; }
    }
    unsigned int b = __float_as_uint(best);
    b = (b & 0x80000000u) ? ~b : (b | 0x80000000u);
    const unsigned long long kk =
        ((unsigned long long)b << 32) | (unsigned int)(KCB - 1 - besti);
    atomicMax(&key[tok0 + tid], kk);
  }
}

// ---------------- finalize per token ----------------
__global__ __launch_bounds__(256) void k_final(const float* __restrict__ z,
                                               const float* __restrict__ cb,
                                               const unsigned long long* __restrict__ key,
                                               float* __restrict__ out,
                                               float* __restrict__ hist,
                                               float* __restrict__ comm) {
  const int lane = threadIdx.x & 63;
  const int wv   = threadIdx.x >> 6;
  const int tok  = blockIdx.x * 4 + wv;
  const unsigned long long kk = key[tok];
  int bi = KCB - 1 - (int)(kk & 0xFFFFFFFFu);
  bi = min(max(bi, 0), KCB - 1);
  const float4 c  = *(const float4*)(cb + (size_t)bi * DDIM + 4 * lane);
  const float4 zv = *(const float4*)(z + (size_t)tok * DDIM + 4 * lane);
  float4 q;
  q.x = zv.x + (c.x - zv.x);
  q.y = zv.y + (c.y - zv.y);
  q.z = zv.z + (c.z - zv.z);
  q.w = zv.w + (c.w - zv.w);
  const size_t o = (size_t)tok * DDIM + 4 * lane;
  *(float4*)(out + OUT_ZQ  + o) = q;
  *(float4*)(out + OUT_EMB + o) = c;
  const float dx = q.x - zv.x, dy = q.y - zv.y, dz = q.z - zv.z, dw = q.w - zv.w;
  float s = dx * dx + dy * dy + dz * dz + dw * dw;
  #pragma unroll
  for (int o2 = 32; o2 > 0; o2 >>= 1) s += __shfl_down(s, o2);
  if (lane == 0) {
    atomicAdd(comm, s);
    atomicAdd(&hist[bi], 1.0f);
    out[OUT_IDX + tok] = (float)bi;
  }
}

// ---------------- scalars ----------------
__global__ __launch_bounds__(1024) void k_scal(const float* __restrict__ cu,
                                               const float* __restrict__ hist,
                                               const float* __restrict__ comm,
                                               float* __restrict__ out) {
  __shared__ float red[1024];
  const int tid = threadIdx.x;
  float us[4];
  float s = 0.0f;
  #pragma unroll
  for (int j = 0; j < 4; ++j) {
    const int k = tid * 4 + j;
    us[j] = cu[k] * 0.99f + hist[k];
    s += us[j];
  }
  red[tid] = s; __syncthreads();
  for (int o = 512; o > 0; o >>= 1) {
    if (tid < o) red[tid] += red[tid + o];
    __syncthreads();
  }
  const float usum = red[0];
  __syncthreads();
  float e = 0.0f;
  #pragma unroll
  for (int j = 0; j < 4; ++j) {
    const float p = (usum > 0.0f) ? (us[j] / (usum + GEPS)) : (1.0f / (float)KCB);
    e -= p * logf(p + GEPS);
  }
  red[tid] = e; __syncthreads();
  for (int o = 512; o > 0; o >>= 1) {
    if (tid < o) red[tid] += red[tid + o];
    __syncthreads();
  }
  if (tid == 0) {
    const float entropy = red[0];
    out[OUT_SCAL + 0] = comm[0] / (float)((size_t)NTOK * DDIM);
    out[OUT_SCAL + 1] = expf(entropy);
    out[OUT_SCAL + 2] = entropy;
  }
}

extern "C" void kernel_launch(void* const* d_in, const int* in_sizes, int n_in,
                              void* d_out, int out_size, void* d_ws, size_t ws_size,
                              hipStream_t stream) {
  const float* z  = (const float*)d_in[0];
  const float* u  = (const float*)d_in[1];
  const float* cb = (const float*)d_in[2];
  const float* cu = (const float*)d_in[3];

  float* ws   = (float*)d_ws;
  float* esq  = ws + WS_ESQ;
  float* zsq  = ws + WS_ZSQ;
  float* keyf = ws + WS_KEY;
  unsigned long long* key = (unsigned long long*)keyf;
  float* hist = ws + WS_HIST;
  float* comm = ws + WS_COMM;
  float* out  = (float*)d_out;

  k_prep<<<dim3((KCB + NTOK) / 4), dim3(256), 0, stream>>>(cb, z, esq, zsq, keyf, hist, comm);

  if (ws_size >= (size_t)WS_END * 4) {
    unsigned short* zh = (unsigned short*)(ws + WS_ZH);
    unsigned short* zm = (unsigned short*)(ws + WS_ZM);
    unsigned short* zl = (unsigned short*)(ws + WS_ZL);
    unsigned short* ch = (unsigned short*)(ws + WS_CH);
    unsigned short* cm = (unsigned short*)(ws + WS_CM);
    unsigned short* cl = (unsigned short*)(ws + WS_CL);
    k_planes<<<dim3((NTOK + KCB) * DDIM / 4 / 256), dim3(256), 0, stream>>>(
        z, cb, zh, zm, zl, ch, cm, cl);
    k_mfma<<<dim3(KCB / 128, NTOK / 64), dim3(256), 0, stream>>>(
        zh, zm, zl, ch, cm, cl, u, esq, zsq, key);
  } else {
    k_score<<<dim3(NTOK / BT, KCB / BK), dim3(256), 0, stream>>>(z, u, cb, esq, zsq, key);
  }

  k_final<<<dim3(NTOK / 4), dim3(256), 0, stream>>>(z, cb, key, out, hist, comm);
  k_scal <<<dim3(1), dim3(1024), 0, stream>>>(cu, hist, comm, out);
}

// Round 8
// 280.552 us; speedup vs baseline: 2.4030x; 1.4403x over previous
//
#include <hip/hip_runtime.h>
#include <math.h>

#define NTOK 8192
#define DDIM 256
#define KCB  4096
#define GEPS 1e-10f

typedef __attribute__((ext_vector_type(8))) short short8;   // 8 bf16 (4 VGPR)
typedef __attribute__((ext_vector_type(4))) float f32x4;

// ws layout (float units)
#define WS_ESQ  0
#define WS_ZSQ  (WS_ESQ + KCB)          // 4096
#define WS_KEY  (WS_ZSQ + NTOK)         // 12288 (u64[8192])
#define WS_HIST (WS_KEY + 2 * NTOK)     // 28672
#define WS_COMM (WS_HIST + KCB)         // 32768
#define WS_ZH   32776                   // 16B-aligned
#define WS_ZM   (WS_ZH + NTOK * DDIM / 2)
#define WS_ZL   (WS_ZM + NTOK * DDIM / 2)
#define WS_CH   (WS_ZL + NTOK * DDIM / 2)
#define WS_CM   (WS_CH + KCB * DDIM / 2)
#define WS_CL   (WS_CM + KCB * DDIM / 2)
#define WS_END  (WS_CL + KCB * DDIM / 2)    // ≈ 19.01 MB

// plane offsets from zh in USHORT units (planes are contiguous in ws)
#define PO_ZH 0
#define PO_ZM (NTOK * DDIM)
#define PO_ZL (2 * NTOK * DDIM)
#define PO_CH (3 * NTOK * DDIM)
#define PO_CM (3 * NTOK * DDIM + KCB * DDIM)
#define PO_CL (3 * NTOK * DDIM + 2 * KCB * DDIM)

// out offsets (f32): z_q, embedding, indices, commitment, perplexity, entropy
#define OUT_ZQ   0
#define OUT_EMB  (NTOK * DDIM)
#define OUT_IDX  (2 * NTOK * DDIM)
#define OUT_SCAL (2 * NTOK * DDIM + NTOK)

__device__ __forceinline__ unsigned short f2bf(float x) {   // RNE f32->bf16
  unsigned int u = __float_as_uint(x);
  u += 0x7FFFu + ((u >> 16) & 1u);
  return (unsigned short)(u >> 16);
}
__device__ __forceinline__ float bf2f(unsigned short h) {
  return __uint_as_float(((unsigned int)h) << 16);
}

__device__ __forceinline__ void gload16(const void* g, void* l) {
  __builtin_amdgcn_global_load_lds(
      (const __attribute__((address_space(1))) unsigned int*)g,
      (__attribute__((address_space(3))) unsigned int*)l, 16, 0, 0);
}

// ---------------- prep ----------------
__global__ __launch_bounds__(256) void k_prep(const float* __restrict__ cb,
                                              const float* __restrict__ z,
                                              float* __restrict__ esq,
                                              float* __restrict__ zsq,
                                              float* __restrict__ keyf,
                                              float* __restrict__ hist,
                                              float* __restrict__ comm) {
  const int lane = threadIdx.x & 63;
  const int wv   = threadIdx.x >> 6;
  const int row  = blockIdx.x * 4 + wv;   // 0..12287
  const float* src = (row < KCB) ? (cb + (size_t)row * DDIM)
                                 : (z  + (size_t)(row - KCB) * DDIM);
  float4 v = *(const float4*)(src + 4 * lane);
  float s = v.x * v.x + v.y * v.y + v.z * v.z + v.w * v.w;
  #pragma unroll
  for (int o = 32; o > 0; o >>= 1) s += __shfl_down(s, o);
  if (lane == 0) {
    if (row < KCB) esq[row] = s;
    else           zsq[row - KCB] = s;
  }
  const int gid = blockIdx.x * 256 + threadIdx.x;
  if (gid < 2 * NTOK) keyf[gid] = 0.0f;
  else if (gid < 2 * NTOK + KCB) hist[gid - 2 * NTOK] = 0.0f;
  else if (gid == 2 * NTOK + KCB) comm[0] = 0.0f;
}

// ---------------- split f32 -> 3 bf16 planes ----------------
__global__ __launch_bounds__(256) void k_planes(const float* __restrict__ z,
                                                const float* __restrict__ cb,
                                                unsigned short* __restrict__ zh,
                                                unsigned short* __restrict__ zm,
                                                unsigned short* __restrict__ zl,
                                                unsigned short* __restrict__ ch,
                                                unsigned short* __restrict__ cm,
                                                unsigned short* __restrict__ cl) {
  const int idx = blockIdx.x * 256 + threadIdx.x;      // float4 index
  const int nz4 = NTOK * DDIM / 4;
  const bool isz = idx < nz4;
  const float4 v = isz ? ((const float4*)z)[idx] : ((const float4*)cb)[idx - nz4];
  const float vv[4] = {v.x, v.y, v.z, v.w};
  ushort4 h4, m4, l4;
  unsigned short* hp = (unsigned short*)&h4;
  unsigned short* mp = (unsigned short*)&m4;
  unsigned short* lp = (unsigned short*)&l4;
  #pragma unroll
  for (int j = 0; j < 4; ++j) {
    const float x  = vv[j];
    const unsigned short h = f2bf(x);
    const float r1 = x - bf2f(h);
    const unsigned short m = f2bf(r1);
    const float r2 = r1 - bf2f(m);
    hp[j] = h; mp[j] = m; lp[j] = f2bf(r2);
  }
  if (isz) {
    ((ushort4*)zh)[idx] = h4; ((ushort4*)zm)[idx] = m4; ((ushort4*)zl)[idx] = l4;
  } else {
    const int o = idx - nz4;
    ((ushort4*)ch)[o] = h4; ((ushort4*)cm)[o] = m4; ((ushort4*)cl)[o] = l4;
  }
}

// ---------------- LDS-staged split-bf16 MFMA GEMM (m97-style) ----------------
// grid (KCB/128, NTOK/128), block 256 = 4 waves (2x2), wave tile 64x64.
// LDS: 6 planes x [128 rows][32 d] bf16 = 48 KB, slot-swizzled (see below).
__global__ __launch_bounds__(256, 2) void k_mfma(const unsigned short* __restrict__ zh,
                                                 const float* __restrict__ u,
                                                 const float* __restrict__ esq,
                                                 const float* __restrict__ zsq,
                                                 unsigned long long* __restrict__ key) {
  __shared__ __align__(1024) unsigned char lbuf[49152];

  const int tid = threadIdx.x;
  const int l   = tid & 63;
  const int wid = tid >> 6;
  const int tok0 = blockIdx.y * 128;
  const int c0   = blockIdx.x * 128;
  const int lrow = l & 15;
  const int lkg  = l >> 4;                  // 0..3 (k-group / global dhalf)
  const int tw = (wid >> 1) * 64;           // wave token base
  const int cw = (wid & 1) * 64;            // wave code base

  // ---- staging lane constants ----
  // chunk c = wid + 4j : plane p=c>>3 (0..5), 16-row group sub=c&7.
  // lane writes LDS byte p*8192 + sub*1024 + l*16  (linear dest for global_load_lds)
  //   = row (sub*16 + l>>2), slot (l&3).  Slot ss at row r stores global dhalf
  //   dh = ss ^ ((r>>2)&3)  -> lane fetches dh = (l&3) ^ (l>>4).
  const int srow = l >> 2;
  const int sdh  = (l & 3) ^ (l >> 4);

  unsigned int srcoff[12];   // ushort-unit offsets from zh
  unsigned int lbase[12];
  #pragma unroll
  for (int j = 0; j < 12; ++j) {
    const int c   = wid + 4 * j;
    const int p   = c >> 3;
    const int sub = c & 7;
    const unsigned int po = (p == 0) ? PO_ZH : (p == 1) ? PO_ZM : (p == 2) ? PO_ZL
                          : (p == 3) ? PO_CH : (p == 4) ? PO_CM : PO_CL;
    const int rbase = ((p < 3) ? tok0 : c0) + sub * 16 + srow;
    srcoff[j] = po + (unsigned int)rbase * DDIM + sdh * 8;
    lbase[j]  = p * 8192 + sub * 1024;
  }

  f32x4 acc[4][4] = {};
  const unsigned int sw = ((unsigned int)(lkg ^ ((lrow >> 2) & 3))) << 4;

  for (int kk = 0; kk < 8; ++kk) {
    __syncthreads();                        // previous K-step fully consumed
    #pragma unroll
    for (int j = 0; j < 12; ++j)
      gload16(zh + srcoff[j] + kk * 32, lbuf + lbase[j]);
    __syncthreads();                        // vmcnt(0) drain: tile visible

    // B fragments: 3 planes x 4 ni (12 ds_read_b128), kept live across mi
    short8 bfr[3][4];
    #pragma unroll
    for (int ni = 0; ni < 4; ++ni) {
      const unsigned int boff = (unsigned int)(cw + ni * 16 + lrow) * 64 + sw;
      bfr[0][ni] = *(const short8*)(lbuf + 24576 + boff);   // bh
      bfr[1][ni] = *(const short8*)(lbuf + 32768 + boff);   // bm
      bfr[2][ni] = *(const short8*)(lbuf + 40960 + boff);   // bl
    }
    #pragma unroll
    for (int mi = 0; mi < 4; ++mi) {
      const unsigned int aoff = (unsigned int)(tw + mi * 16 + lrow) * 64 + sw;
      const short8 ah = *(const short8*)(lbuf + 0     + aoff);
      const short8 am = *(const short8*)(lbuf + 8192  + aoff);
      const short8 al = *(const short8*)(lbuf + 16384 + aoff);
      #pragma unroll
      for (int ni = 0; ni < 4; ++ni) {
        f32x4 a = acc[mi][ni];
        a = __builtin_amdgcn_mfma_f32_16x16x32_bf16(am, bfr[1][ni], a, 0, 0, 0); // mm
        a = __builtin_amdgcn_mfma_f32_16x16x32_bf16(ah, bfr[2][ni], a, 0, 0, 0); // hl
        a = __builtin_amdgcn_mfma_f32_16x16x32_bf16(al, bfr[0][ni], a, 0, 0, 0); // lh
        a = __builtin_amdgcn_mfma_f32_16x16x32_bf16(ah, bfr[1][ni], a, 0, 0, 0); // hm
        a = __builtin_amdgcn_mfma_f32_16x16x32_bf16(am, bfr[0][ni], a, 0, 0, 0); // mh
        a = __builtin_amdgcn_mfma_f32_16x16x32_bf16(ah, bfr[0][ni], a, 0, 0, 0); // hh
        acc[mi][ni] = a;
      }
    }
  }

  // ---- epilogue: score + argmax. C/D: col=l&15, row=(l>>4)*4+reg ----
  float esv[4];
  #pragma unroll
  for (int ni = 0; ni < 4; ++ni) esv[ni] = esq[c0 + cw + ni * 16 + lrow];
  const int rb = lkg * 4;

  #pragma unroll
  for (int mi = 0; mi < 4; ++mi) {
    #pragma unroll
    for (int r = 0; r < 4; ++r) {
      const int t  = tok0 + tw + mi * 16 + rb + r;
      const float zq = zsq[t];
      float bv = -3.402823e38f;
      int   bc = c0 + cw + lrow;
      #pragma unroll
      for (int ni = 0; ni < 4; ++ni) {
        const int c = c0 + cw + ni * 16 + lrow;
        const float uu = u[(size_t)t * KCB + c];
        const float g  = -logf(-logf(uu + GEPS) + GEPS);
        const float s  = -((zq + esv[ni]) - 2.0f * acc[mi][ni][r]) + g;
        if (s > bv) { bv = s; bc = c; }          // ni ascending = code ascending
      }
      #pragma unroll
      for (int m = 1; m < 16; m <<= 1) {
        const float ov = __shfl_xor(bv, m);
        const int   oc = __shfl_xor(bc, m);
        if (ov > bv || (ov == bv && oc < bc)) { bv = ov; bc = oc; }
      }
      if (lrow == 0) {
        unsigned int b = __float_as_uint(bv);
        b = (b & 0x80000000u) ? ~b : (b | 0x80000000u);
        const unsigned long long kk2 =
            ((unsigned long long)b << 32) | (unsigned int)(KCB - 1 - bc);
        atomicMax(&key[t], kk2);
      }
    }
  }
}

// ---------------- fallback f32 path (used only if ws too small) ----------------
#define BT 128
#define BK 128
#define DC 32
#define PS 132
__global__ __launch_bounds__(256) void k_score(const float* __restrict__ z,
                                               const float* __restrict__ u,
                                               const float* __restrict__ cb,
                                               const float* __restrict__ esq,
                                               const float* __restrict__ zsq,
                                               unsigned long long* __restrict__ key) {
  __shared__ float zsm[DC][PS];
  __shared__ float csm[DC][PS];
  const int tid  = threadIdx.x;
  const int tok0 = blockIdx.x * BT;
  const int kb   = blockIdx.y * BK;
  const int tx = tid & 15;
  const int ty = tid >> 4;
  const int srow = tid >> 3;
  const int sc4  = (tid & 7) * 4;
  float acc[8][8] = {};
  float4 zr[4], cr[4];
  #pragma unroll
  for (int j = 0; j < 4; ++j) {
    const int r = srow + 32 * j;
    zr[j] = *(const float4*)(z  + (size_t)(tok0 + r) * DDIM + sc4);
    cr[j] = *(const float4*)(cb + (size_t)(kb  + r) * DDIM + sc4);
  }
  for (int dc = 0; dc < DDIM / DC; ++dc) {
    __syncthreads();
    #pragma unroll
    for (int j = 0; j < 4; ++j) {
      const int r = srow + 32 * j;
      zsm[sc4 + 0][r] = zr[j].x; zsm[sc4 + 1][r] = zr[j].y;
      zsm[sc4 + 2][r] = zr[j].z; zsm[sc4 + 3][r] = zr[j].w;
      csm[sc4 + 0][r] = cr[j].x; csm[sc4 + 1][r] = cr[j].y;
      csm[sc4 + 2][r] = cr[j].z; csm[sc4 + 3][r] = cr[j].w;
    }
    __syncthreads();
    if (dc + 1 < DDIM / DC) {
      const int d0 = (dc + 1) * DC;
      #pragma unroll
      for (int j = 0; j < 4; ++j) {
        const int r = srow + 32 * j;
        zr[j] = *(const float4*)(z  + (size_t)(tok0 + r) * DDIM + d0 + sc4);
        cr[j] = *(const float4*)(cb + (size_t)(kb  + r) * DDIM + d0 + sc4);
      }
    }
    #pragma unroll 4
    for (int d = 0; d < DC; ++d) {
      const float4 za = *(const float4*)&zsm[d][8 * ty];
      const float4 zb = *(const float4*)&zsm[d][8 * ty + 4];
      const float4 ca = *(const float4*)&csm[d][8 * tx];
      const float4 cc = *(const float4*)&csm[d][8 * tx + 4];
      const float zf[8] = {za.x, za.y, za.z, za.w, zb.x, zb.y, zb.z, zb.w};
      const float cf[8] = {ca.x, ca.y, ca.z, ca.w, cc.x, cc.y, cc.z, cc.w};
      #pragma unroll
      for (int i = 0; i < 8; ++i)
        #pragma unroll
        for (int j = 0; j < 8; ++j) acc[i][j] += zf[i] * cf[j];
    }
  }
  const float4 ea = *(const float4*)(esq + kb + 8 * tx);
  const float4 eb = *(const float4*)(esq + kb + 8 * tx + 4);
  const float esa[8] = {ea.x, ea.y, ea.z, ea.w, eb.x, eb.y, eb.z, eb.w};
  float bv[8]; int bj[8];
  #pragma unroll
  for (int i = 0; i < 8; ++i) {
    const int tok = tok0 + 8 * ty + i;
    const float zq = zsq[tok];
    const float4 ua = *(const float4*)(u + (size_t)tok * KCB + kb + 8 * tx);
    const float4 ub = *(const float4*)(u + (size_t)tok * KCB + kb + 8 * tx + 4);
    const float uu[8] = {ua.x, ua.y, ua.z, ua.w, ub.x, ub.y, ub.z, ub.w};
    bv[i] = -3.402823e38f; bj[i] = kb + 8 * tx;
    #pragma unroll
    for (int j = 0; j < 8; ++j) {
      const float g = -logf(-logf(uu[j] + GEPS) + GEPS);
      const float s = -((zq + esa[j]) - 2.0f * acc[i][j]) + g;
      if (s > bv[i]) { bv[i] = s; bj[i] = kb + 8 * tx + j; }
    }
  }
  __syncthreads();
  float* pv = &zsm[0][0];
  int*   pi = (int*)&csm[0][0];
  #pragma unroll
  for (int i = 0; i < 8; ++i) {
    pv[(8 * ty + i) * 16 + tx] = bv[i];
    pi[(8 * ty + i) * 16 + tx] = bj[i];
  }
  __syncthreads();
  if (tid < BT) {
    float best  = pv[tid * 16];
    int   besti = pi[tid * 16];
    for (int x = 1; x < 16; ++x) {
      const float v = pv[tid * 16 + x];
      if (v > best) { best = v; besti = pi[tid * 16 + x]; }
    }
    unsigned int b = __float_as_uint(best);
    b = (b & 0x80000000u) ? ~b : (b | 0x80000000u);
    const unsigned long long kk =
        ((unsigned long long)b << 32) | (unsigned int)(KCB - 1 - besti);
    atomicMax(&key[tok0 + tid], kk);
  }
}

// ---------------- finalize per token ----------------
__global__ __launch_bounds__(256) void k_final(const float* __restrict__ z,
                                               const float* __restrict__ cb,
                                               const unsigned long long* __restrict__ key,
                                               float* __restrict__ out,
                                               float* __restrict__ hist,
                                               float* __restrict__ comm) {
  const int lane = threadIdx.x & 63;
  const int wv   = threadIdx.x >> 6;
  const int tok  = blockIdx.x * 4 + wv;
  const unsigned long long kk = key[tok];
  int bi = KCB - 1 - (int)(kk & 0xFFFFFFFFu);
  bi = min(max(bi, 0), KCB - 1);
  const float4 c  = *(const float4*)(cb + (size_t)bi * DDIM + 4 * lane);
  const float4 zv = *(const float4*)(z + (size_t)tok * DDIM + 4 * lane);
  float4 q;
  q.x = zv.x + (c.x - zv.x);
  q.y = zv.y + (c.y - zv.y);
  q.z = zv.z + (c.z - zv.z);
  q.w = zv.w + (c.w - zv.w);
  const size_t o = (size_t)tok * DDIM + 4 * lane;
  *(float4*)(out + OUT_ZQ  + o) = q;
  *(float4*)(out + OUT_EMB + o) = c;
  const float dx = q.x - zv.x, dy = q.y - zv.y, dz = q.z - zv.z, dw = q.w - zv.w;
  float s = dx * dx + dy * dy + dz * dz + dw * dw;
  #pragma unroll
  for (int o2 = 32; o2 > 0; o2 >>= 1) s += __shfl_down(s, o2);
  if (lane == 0) {
    atomicAdd(comm, s);
    atomicAdd(&hist[bi], 1.0f);
    out[OUT_IDX + tok] = (float)bi;
  }
}

// ---------------- scalars ----------------
__global__ __launch_bounds__(1024) void k_scal(const float* __restrict__ cu,
                                               const float* __restrict__ hist,
                                               const float* __restrict__ comm,
                                               float* __restrict__ out) {
  __shared__ float red[1024];
  const int tid = threadIdx.x;
  float us[4];
  float s = 0.0f;
  #pragma unroll
  for (int j = 0; j < 4; ++j) {
    const int k = tid * 4 + j;
    us[j] = cu[k] * 0.99f + hist[k];
    s += us[j];
  }
  red[tid] = s; __syncthreads();
  for (int o = 512; o > 0; o >>= 1) {
    if (tid < o) red[tid] += red[tid + o];
    __syncthreads();
  }
  const float usum = red[0];
  __syncthreads();
  float e = 0.0f;
  #pragma unroll
  for (int j = 0; j < 4; ++j) {
    const float p = (usum > 0.0f) ? (us[j] / (usum + GEPS)) : (1.0f / (float)KCB);
    e -= p * logf(p + GEPS);
  }
  red[tid] = e; __syncthreads();
  for (int o = 512; o > 0; o >>= 1) {
    if (tid < o) red[tid] += red[tid + o];
    __syncthreads();
  }
  if (tid == 0) {
    const float entropy = red[0];
    out[OUT_SCAL + 0] = comm[0] / (float)((size_t)NTOK * DDIM);
    out[OUT_SCAL + 1] = expf(entropy);
    out[OUT_SCAL + 2] = entropy;
  }
}

extern "C" void kernel_launch(void* const* d_in, const int* in_sizes, int n_in,
                              void* d_out, int out_size, void* d_ws, size_t ws_size,
                              hipStream_t stream) {
  const float* z  = (const float*)d_in[0];
  const float* u  = (const float*)d_in[1];
  const float* cb = (const float*)d_in[2];
  const float* cu = (const float*)d_in[3];

  float* ws   = (float*)d_ws;
  float* esq  = ws + WS_ESQ;
  float* zsq  = ws + WS_ZSQ;
  float* keyf = ws + WS_KEY;
  unsigned long long* key = (unsigned long long*)keyf;
  float* hist = ws + WS_HIST;
  float* comm = ws + WS_COMM;
  float* out  = (float*)d_out;

  k_prep<<<dim3((KCB + NTOK) / 4), dim3(256), 0, stream>>>(cb, z, esq, zsq, keyf, hist, comm);

  if (ws_size >= (size_t)WS_END * 4) {
    unsigned short* zh = (unsigned short*)(ws + WS_ZH);
    unsigned short* zm = (unsigned short*)(ws + WS_ZM);
    unsigned short* zl = (unsigned short*)(ws + WS_ZL);
    unsigned short* ch = (unsigned short*)(ws + WS_CH);
    unsigned short* cm = (unsigned short*)(ws + WS_CM);
    unsigned short* cl = (unsigned short*)(ws + WS_CL);
    k_planes<<<dim3((NTOK + KCB) * DDIM / 4 / 256), dim3(256), 0, stream>>>(
        z, cb, zh, zm, zl, ch, cm, cl);
    k_mfma<<<dim3(KCB / 128, NTOK / 128), dim3(256), 0, stream>>>(
        zh, u, esq, zsq, key);
  } else {
    k_score<<<dim3(NTOK / BT, KCB / BK), dim3(256), 0, stream>>>(z, u, cb, esq, zsq, key);
  }

  k_final<<<dim3(NTOK / 4), dim3(256), 0, stream>>>(z, cb, key, out, hist, comm);
  k_scal <<<dim3(1), dim3(1024), 0, stream>>>(cu, hist, comm, out);
}